// Round 21
// baseline (112.762 us; speedup 1.0000x reference)
//
#include <hip/hip_runtime.h>
#include <hip/hip_fp16.h>
#include <math.h>

// Softmax splatting: B=8, C=4, H=512, W=960, fp32.
// R21: R20 with the merge's scattered frame loads HOISTED to kernel head
// (thread tid<cnt preloads its bucket entry + 4 frame values into registers
// right after staging; ~900cy latency hides under the ~70us gather).
// Merge tail is then register-ready atomics only.

#define EPS 1e-7f

constexpr int B = 8, C = 4, H = 512, W = 960;
constexpr int HW = H * W;            // 491520
constexpr int CHW = C * HW;          // 1966080
constexpr int NPIX = B * HW;         // 3932160

constexpr int TX = 32, TY = 32;      // output tile
constexpr int RAD = 3;               // candidate window half-width
constexpr int GROWS = 38;            // staged rows: y0-3 .. y0+34
constexpr int QXQ = 10;              // float4-quads per staged row (40 cols)
constexpr int NQUAD = QXQ * GROWS;   // 380
constexpr int LSTRIDE = 42;          // cell stride per row
constexpr int NCELL = GROWS * LSTRIDE;  // 1596

constexpr int NTILE_X = W / TX;      // 30
constexpr int NTILE = NTILE_X * (H / TY);  // 480 per batch
constexpr int BUCKET_CAP = 64;       // entries per tile bucket (mean ~5.5)

struct alignas(8) HPack { __half2 a; __half2 b; };   // (f0,f1),(f2,f3)

// ---- prepass: corners escaping the +-RAD box -> per-tile bucket lists
// Slim entries: (cell, src_idx, w, im). No frame reads here.
__global__ __launch_bounds__(256) void outlier_pass(
    const float* __restrict__ flow,
    const float* __restrict__ imp,
    int* __restrict__ bcnt,          // [B*NTILE]
    float* __restrict__ bucket)      // [B*NTILE * BUCKET_CAP * 4]
{
    int g = blockIdx.x * blockDim.x + threadIdx.x;
    if (g >= NPIX / 4) return;
    const int QHW = HW / 4;
    int b = g / QHW;
    int q = g - b * QHW;
    int p0 = q * 4;
    int sy = p0 / W;
    int sx0 = p0 - sy * W;            // W%4==0 -> quad within one row

    const size_t flb = (size_t)b * 2 * HW;
    float4 vfx = *(const float4*)(flow + flb + p0);
    float4 vfy = *(const float4*)(flow + flb + HW + p0);
    float aflx[4] = {vfx.x, vfx.y, vfx.z, vfx.w};
    float afly[4] = {vfy.x, vfy.y, vfy.z, vfy.w};

    const size_t ib = (size_t)b * HW;

    #pragma unroll
    for (int k = 0; k < 4; ++k) {
        float flx = aflx[k];
        float fly = afly[k];
        // |fl| <= RAD-1 guarantees both corners within +-RAD box
        if (fabsf(flx) <= (float)(RAD - 1) && fabsf(fly) <= (float)(RAD - 1)) continue;

        int sx = sx0 + k;
        int p = p0 + k;
        float tx = (float)sx + flx;
        float ty = (float)sy + fly;
        float fxf = floorf(tx);
        float fyf = floorf(ty);
        float dx = tx - fxf;
        float dy = ty - fyf;
        int fx = (int)fxf;
        int fy = (int)fyf;

        float im = __expf(imp[ib + p]);

        #pragma unroll
        for (int cyi = 0; cyi < 2; ++cyi) {
            #pragma unroll
            for (int cxi = 0; cxi < 2; ++cxi) {
                int cx = fx + cxi;
                int cy = fy + cyi;
                if ((unsigned)cx >= (unsigned)W || (unsigned)cy >= (unsigned)H) continue;
                int ax = cx - sx; if (ax < 0) ax = -ax;
                int ay = cy - sy; if (ay < 0) ay = -ay;
                if (ax <= RAD && ay <= RAD) continue;   // covered by owner's gather
                float w = (cxi ? dx : 1.0f - dx) * (cyi ? dy : 1.0f - dy);
                int tile = b * NTILE + (cy >> 5) * NTILE_X + (cx >> 5);
                int e = atomicAdd(&bcnt[tile], 1);
                if (e < BUCKET_CAP) {
                    float* ent = bucket + ((size_t)tile * BUCKET_CAP + e) * 4;
                    ent[0] = __int_as_float((cy & 31) * TX + (cx & 31));
                    ent[1] = __int_as_float(p);
                    ent[2] = w;
                    ent[3] = im;
                }
            }
        }
    }
}

// ---- main: stage region, 2x2-quad register gather, bucket merge, store
__global__ __launch_bounds__(256) void splat_gather(
    const float* __restrict__ frame,
    const float* __restrict__ flow,
    const float* __restrict__ imp,
    float* __restrict__ out,
    const int* __restrict__ bcnt,
    const float* __restrict__ bucket)
{
    // 31.9 KB -> 5 blocks/CU. Partitioned; aliased by the bucket merge.
    __shared__ float smem[5 * NCELL];              // 7980 floats
    float2* XY = (float2*)smem;                    // (tx, ty) f32
    float*  IM = smem + 2 * NCELL;                 // im f32
    HPack*  CH = (HPack*)(smem + 3 * NCELL);       // f0..f3 f16

    const int tid = threadIdx.x;
    const int x0 = blockIdx.x * TX;
    const int y0 = blockIdx.y * TY;
    const int b  = blockIdx.z;

    const float* fxp   = flow + (size_t)b * 2 * HW;
    const float* fyp   = fxp + HW;
    const float* imp_p = imp + (size_t)b * HW;
    const float* c0p   = frame + (size_t)b * CHW;
    const float* c1p   = c0p + HW;
    const float* c2p   = c1p + HW;
    const float* c3p   = c2p + HW;

    // ---------- stage 40x38 region, premultiplied, absolute target coords
    #pragma unroll
    for (int it = 0; it < 2; ++it) {
        int q = tid + it * 256;
        if (q < NQUAD) {
            int r = q / QXQ;
            int c = q - r * QXQ;
            int sy = y0 - RAD + r;          // rows y0-3 .. y0+34
            int sx0 = x0 - 4 + 4 * c;       // cols x0-4 .. x0+35 (16B aligned)
            int p = sy * W + sx0;
            int pc = p < 0 ? 0 : (p > HW - 4 ? HW - 4 : p);
            bool qv = ((unsigned)sy < (unsigned)H) & ((unsigned)sx0 < (unsigned)W);

            float4 vfx = *(const float4*)(fxp + pc);
            float4 vfy = *(const float4*)(fyp + pc);
            float4 vim = *(const float4*)(imp_p + pc);
            float4 v0  = *(const float4*)(c0p + pc);
            float4 v1  = *(const float4*)(c1p + pc);
            float4 v2  = *(const float4*)(c2p + pc);
            float4 v3  = *(const float4*)(c3p + pc);

            float aflx[4] = {vfx.x, vfx.y, vfx.z, vfx.w};
            float afly[4] = {vfy.x, vfy.y, vfy.z, vfy.w};
            float aim [4] = {vim.x, vim.y, vim.z, vim.w};
            float a0  [4] = {v0.x,  v0.y,  v0.z,  v0.w};
            float a1  [4] = {v1.x,  v1.y,  v1.z,  v1.w};
            float a2  [4] = {v2.x,  v2.y,  v2.z,  v2.w};
            float a3  [4] = {v3.x,  v3.y,  v3.z,  v3.w};

            int base = r * LSTRIDE + c * 4;
            #pragma unroll
            for (int k = 0; k < 4; ++k) {
                float im = qv ? __expf(aim[k]) : 0.0f;   // im=0 kills invalid cells
                float txv = (float)(sx0 + k) + aflx[k];
                float tyv = (float)sy + afly[k];
                XY[base + k] = make_float2(txv, tyv);
                IM[base + k] = im;
                HPack hp;
                hp.a = __floats2half2_rn(a0[k] * im, a1[k] * im);
                hp.b = __floats2half2_rn(a2[k] * im, a3[k] * im);
                CH[base + k] = hp;
            }
        }
    }
    __syncthreads();

    // ---------- hoisted bucket-entry preload (latency hides under the gather)
    const int tile = b * NTILE + blockIdx.y * NTILE_X + blockIdx.x;
    int cnt = bcnt[tile];
    if (cnt > BUCKET_CAP) cnt = BUCKET_CAP;
    const bool have = (tid < cnt);
    int ecell = 0;
    float ev0 = 0.f, ev1 = 0.f, ev2 = 0.f, ev3 = 0.f, eiw = 0.f;
    if (have) {
        float4 e4 = *(const float4*)(bucket + (size_t)(tile * BUCKET_CAP + tid) * 4);
        ecell = __float_as_int(e4.x);
        int p = __float_as_int(e4.y);
        eiw = e4.w * e4.z;                // im * w
        ev0 = c0p[p] * eiw;
        ev1 = c1p[p] * eiw;
        ev2 = c2p[p] * eiw;
        ev3 = c3p[p] * eiw;
    }

    // ---------- 2x2 quad register gather: thread owns rows {2qy,2qy+1},
    //            cols {2qx, 2qx+1} of the tile
    const int qx = tid & 15;
    const int qy = tid >> 4;
    const float ox0f = (float)(x0 + 2 * qx);
    const float oy0f = (float)(y0 + 2 * qy);

    float accw[4] = {0.f, 0.f, 0.f, 0.f};
    float acc0[4] = {0.f, 0.f, 0.f, 0.f};
    float acc1[4] = {0.f, 0.f, 0.f, 0.f};
    float acc2[4] = {0.f, 0.f, 0.f, 0.f};
    float acc3[4] = {0.f, 0.f, 0.f, 0.f};

    // staged row r = 2qy + dyi; staged col c = 2qx + 1 + dxi
    for (int dyi = 0; dyi < 8; ++dyi) {
        int rowoff = (2 * qy + dyi) * LSTRIDE + 2 * qx + 1;
        #pragma unroll
        for (int dxi = 0; dxi < 8; ++dxi) {
            float2 xy = XY[rowoff + dxi];
            float ddy = xy.y - oy0f;
            float wy0 = (dyi <= 6) ? fmaxf(0.0f, 1.0f - fabsf(ddy))        : 0.0f;
            float wy1 = (dyi >= 1) ? fmaxf(0.0f, 1.0f - fabsf(ddy - 1.0f)) : 0.0f;
            if (wy0 + wy1 > 0.0f) {
                float ddx = xy.x - ox0f;
                float wx0 = (dxi <= 6) ? fmaxf(0.0f, 1.0f - fabsf(ddx))        : 0.0f;
                float wx1 = (dxi >= 1) ? fmaxf(0.0f, 1.0f - fabsf(ddx - 1.0f)) : 0.0f;
                float t00 = wy0 * wx0, t01 = wy0 * wx1;
                float t10 = wy1 * wx0, t11 = wy1 * wx1;
                if ((t00 + t01) + (t10 + t11) > 0.0f) {   // any-hit
                    float im = IM[rowoff + dxi];
                    HPack hp = CH[rowoff + dxi];
                    float2 f01 = __half22float2(hp.a);
                    float2 f23 = __half22float2(hp.b);
                    accw[0] = fmaf(im, t00, accw[0]);
                    accw[1] = fmaf(im, t01, accw[1]);
                    accw[2] = fmaf(im, t10, accw[2]);
                    accw[3] = fmaf(im, t11, accw[3]);
                    acc0[0] = fmaf(f01.x, t00, acc0[0]);
                    acc0[1] = fmaf(f01.x, t01, acc0[1]);
                    acc0[2] = fmaf(f01.x, t10, acc0[2]);
                    acc0[3] = fmaf(f01.x, t11, acc0[3]);
                    acc1[0] = fmaf(f01.y, t00, acc1[0]);
                    acc1[1] = fmaf(f01.y, t01, acc1[1]);
                    acc1[2] = fmaf(f01.y, t10, acc1[2]);
                    acc1[3] = fmaf(f01.y, t11, acc1[3]);
                    acc2[0] = fmaf(f23.x, t00, acc2[0]);
                    acc2[1] = fmaf(f23.x, t01, acc2[1]);
                    acc2[2] = fmaf(f23.x, t10, acc2[2]);
                    acc2[3] = fmaf(f23.x, t11, acc2[3]);
                    acc3[0] = fmaf(f23.y, t00, acc3[0]);
                    acc3[1] = fmaf(f23.y, t01, acc3[1]);
                    acc3[2] = fmaf(f23.y, t10, acc3[2]);
                    acc3[3] = fmaf(f23.y, t11, acc3[3]);
                }
            }
        }
    }

    // ---------- per-tile bucket merge (register-ready; aliases smem)
    __syncthreads();
    if (cnt > 0) {                                     // uniform branch
        float* oacc = smem;                            // 5*1024 floats
        for (int i = tid; i < 5 * 1024; i += 256) oacc[i] = 0.0f;
        __syncthreads();
        if (have) {
            atomicAdd(&oacc[0 * 1024 + ecell], ev0);
            atomicAdd(&oacc[1 * 1024 + ecell], ev1);
            atomicAdd(&oacc[2 * 1024 + ecell], ev2);
            atomicAdd(&oacc[3 * 1024 + ecell], ev3);
            atomicAdd(&oacc[4 * 1024 + ecell], eiw);
        }
        __syncthreads();
        #pragma unroll
        for (int k = 0; k < 2; ++k) {
            #pragma unroll
            for (int j = 0; j < 2; ++j) {
                int cell = (2 * qy + k) * TX + 2 * qx + j;
                int a = k * 2 + j;
                acc0[a] += oacc[0 * 1024 + cell];
                acc1[a] += oacc[1 * 1024 + cell];
                acc2[a] += oacc[2 * 1024 + cell];
                acc3[a] += oacc[3 * 1024 + cell];
                accw[a] += oacc[4 * 1024 + cell];
            }
        }
    }

    // ---------- fused normalize + float2 stores (lanes qx-consecutive)
    float inv[4];
    #pragma unroll
    for (int a = 0; a < 4; ++a) inv[a] = 1.0f / (accw[a] + EPS);

    #pragma unroll
    for (int k = 0; k < 2; ++k) {
        size_t obase = (size_t)b * CHW + (size_t)(y0 + 2 * qy + k) * W + (x0 + 2 * qx);
        int a0i = k * 2, a1i = k * 2 + 1;
        *(float2*)(out + obase + 0 * HW) = make_float2(acc0[a0i] * inv[a0i], acc0[a1i] * inv[a1i]);
        *(float2*)(out + obase + 1 * HW) = make_float2(acc1[a0i] * inv[a0i], acc1[a1i] * inv[a1i]);
        *(float2*)(out + obase + 2 * HW) = make_float2(acc2[a0i] * inv[a0i], acc2[a1i] * inv[a1i]);
        *(float2*)(out + obase + 3 * HW) = make_float2(acc3[a0i] * inv[a0i], acc3[a1i] * inv[a1i]);
    }
}

extern "C" void kernel_launch(void* const* d_in, const int* in_sizes, int n_in,
                              void* d_out, int out_size, void* d_ws, size_t ws_size,
                              hipStream_t stream) {
    const float* frame = (const float*)d_in[0];
    const float* flow  = (const float*)d_in[1];
    const float* imp   = (const float*)d_in[2];
    float* out = (float*)d_out;

    int*   bcnt   = (int*)d_ws;                         // 3840 * 4 B
    float* bucket = (float*)((char*)d_ws + 16384);      // 3840*64*16 B = 3.9 MB

    hipMemsetAsync(bcnt, 0, B * NTILE * sizeof(int), stream);

    outlier_pass<<<(NPIX / 4 + 255) / 256, 256, 0, stream>>>(flow, imp, bcnt, bucket);

    dim3 grid(W / TX, H / TY, B);   // 30 x 16 x 8
    splat_gather<<<grid, 256, 0, stream>>>(frame, flow, imp, out, bcnt, bucket);
}

// Round 22
// 103.560 us; speedup vs baseline: 1.0889x; 1.0889x over previous
//
#include <hip/hip_runtime.h>
#include <hip/hip_fp16.h>
#include <math.h>

// Softmax splatting: B=8, C=4, H=512, W=960, fp32.
// R22: splat_gather = byte-identical R19 (proven 82.9 us; merge at tail,
// fat self-contained bucket entries). outlier_pass = escape-flags FIRST,
// imp/frame reads only for the ~0.5% emitting pixels.

#define EPS 1e-7f

constexpr int B = 8, C = 4, H = 512, W = 960;
constexpr int HW = H * W;            // 491520
constexpr int CHW = C * HW;          // 1966080
constexpr int NPIX = B * HW;         // 3932160

constexpr int TX = 32, TY = 32;      // output tile
constexpr int RAD = 3;               // candidate window half-width
constexpr int GROWS = 38;            // staged rows: y0-3 .. y0+34
constexpr int QXQ = 10;              // float4-quads per staged row (40 cols)
constexpr int NQUAD = QXQ * GROWS;   // 380
constexpr int LSTRIDE = 42;          // cell stride per row
constexpr int NCELL = GROWS * LSTRIDE;  // 1596

constexpr int NTILE_X = W / TX;      // 30
constexpr int NTILE = NTILE_X * (H / TY);  // 480 per batch
constexpr int BUCKET_CAP = 64;       // entries per tile bucket (mean ~5.5)

struct alignas(8) HPack { __half2 a; __half2 b; };   // (f0,f1),(f2,f3)

// ---- prepass: corners escaping the +-RAD box -> per-tile bucket lists.
// Escape flags computed FIRST; imp/frame read only when emitting (rare).
__global__ __launch_bounds__(256) void outlier_pass(
    const float* __restrict__ frame,
    const float* __restrict__ flow,
    const float* __restrict__ imp,
    int* __restrict__ bcnt,          // [B*NTILE]
    float* __restrict__ bucket)      // [B*NTILE * BUCKET_CAP * 8]
{
    int g = blockIdx.x * blockDim.x + threadIdx.x;
    if (g >= NPIX / 4) return;
    const int QHW = HW / 4;
    int b = g / QHW;
    int q = g - b * QHW;
    int p0 = q * 4;
    int sy = p0 / W;
    int sx0 = p0 - sy * W;            // W%4==0 -> quad within one row

    const size_t flb = (size_t)b * 2 * HW;
    float4 vfx = *(const float4*)(flow + flb + p0);
    float4 vfy = *(const float4*)(flow + flb + HW + p0);
    float aflx[4] = {vfx.x, vfx.y, vfx.z, vfx.w};
    float afly[4] = {vfy.x, vfy.y, vfy.z, vfy.w};

    const size_t fb = (size_t)b * CHW;
    const size_t ib = (size_t)b * HW;

    #pragma unroll
    for (int k = 0; k < 4; ++k) {
        float flx = aflx[k];
        float fly = afly[k];
        // |fl| <= RAD-1 guarantees both corners within +-RAD box
        if (fabsf(flx) <= (float)(RAD - 1) && fabsf(fly) <= (float)(RAD - 1)) continue;

        int sx = sx0 + k;
        int p = p0 + k;
        float tx = (float)sx + flx;
        float ty = (float)sy + fly;
        float fxf = floorf(tx);
        float fyf = floorf(ty);
        float dx = tx - fxf;
        float dy = ty - fyf;
        int fx = (int)fxf;
        int fy = (int)fyf;

        // escape flags first — no memory traffic unless something emits
        bool esc[4];
        bool any = false;
        #pragma unroll
        for (int ci = 0; ci < 4; ++ci) {
            int cx = fx + (ci & 1);
            int cy = fy + (ci >> 1);
            bool valid = ((unsigned)cx < (unsigned)W) & ((unsigned)cy < (unsigned)H);
            int ax = cx - sx; if (ax < 0) ax = -ax;
            int ay = cy - sy; if (ay < 0) ay = -ay;
            esc[ci] = valid & ((ax > RAD) | (ay > RAD));
            any |= esc[ci];
        }
        if (!any) continue;

        float im = __expf(imp[ib + p]);
        float f0 = frame[fb + 0 * HW + p] * im;
        float f1 = frame[fb + 1 * HW + p] * im;
        float f2 = frame[fb + 2 * HW + p] * im;
        float f3 = frame[fb + 3 * HW + p] * im;

        #pragma unroll
        for (int ci = 0; ci < 4; ++ci) {
            if (!esc[ci]) continue;
            int cxi = ci & 1, cyi = ci >> 1;
            int cx = fx + cxi;
            int cy = fy + cyi;
            float w = (cxi ? dx : 1.0f - dx) * (cyi ? dy : 1.0f - dy);
            int tile = b * NTILE + (cy >> 5) * NTILE_X + (cx >> 5);
            int e = atomicAdd(&bcnt[tile], 1);
            if (e < BUCKET_CAP) {
                float* ent = bucket + ((size_t)tile * BUCKET_CAP + e) * 8;
                ent[0] = __int_as_float((cy & 31) * TX + (cx & 31));
                ent[1] = f0 * w;
                ent[2] = f1 * w;
                ent[3] = f2 * w;
                ent[4] = f3 * w;
                ent[5] = im * w;
            }
        }
    }
}

// ---- main: stage region, 2x2-quad register gather, bucket merge, store
__global__ __launch_bounds__(256) void splat_gather(
    const float* __restrict__ frame,
    const float* __restrict__ flow,
    const float* __restrict__ imp,
    float* __restrict__ out,
    const int* __restrict__ bcnt,
    const float* __restrict__ bucket)
{
    // 31.9 KB -> 5 blocks/CU. Partitioned; aliased by the bucket merge.
    __shared__ float smem[5 * NCELL];              // 7980 floats
    float2* XY = (float2*)smem;                    // (tx, ty) f32
    float*  IM = smem + 2 * NCELL;                 // im f32
    HPack*  CH = (HPack*)(smem + 3 * NCELL);       // f0..f3 f16

    const int tid = threadIdx.x;
    const int x0 = blockIdx.x * TX;
    const int y0 = blockIdx.y * TY;
    const int b  = blockIdx.z;

    const float* fxp   = flow + (size_t)b * 2 * HW;
    const float* fyp   = fxp + HW;
    const float* imp_p = imp + (size_t)b * HW;
    const float* c0p   = frame + (size_t)b * CHW;
    const float* c1p   = c0p + HW;
    const float* c2p   = c1p + HW;
    const float* c3p   = c2p + HW;

    // ---------- stage 40x38 region, premultiplied, absolute target coords
    #pragma unroll
    for (int it = 0; it < 2; ++it) {
        int q = tid + it * 256;
        if (q < NQUAD) {
            int r = q / QXQ;
            int c = q - r * QXQ;
            int sy = y0 - RAD + r;          // rows y0-3 .. y0+34
            int sx0 = x0 - 4 + 4 * c;       // cols x0-4 .. x0+35 (16B aligned)
            int p = sy * W + sx0;
            int pc = p < 0 ? 0 : (p > HW - 4 ? HW - 4 : p);
            bool qv = ((unsigned)sy < (unsigned)H) & ((unsigned)sx0 < (unsigned)W);

            float4 vfx = *(const float4*)(fxp + pc);
            float4 vfy = *(const float4*)(fyp + pc);
            float4 vim = *(const float4*)(imp_p + pc);
            float4 v0  = *(const float4*)(c0p + pc);
            float4 v1  = *(const float4*)(c1p + pc);
            float4 v2  = *(const float4*)(c2p + pc);
            float4 v3  = *(const float4*)(c3p + pc);

            float aflx[4] = {vfx.x, vfx.y, vfx.z, vfx.w};
            float afly[4] = {vfy.x, vfy.y, vfy.z, vfy.w};
            float aim [4] = {vim.x, vim.y, vim.z, vim.w};
            float a0  [4] = {v0.x,  v0.y,  v0.z,  v0.w};
            float a1  [4] = {v1.x,  v1.y,  v1.z,  v1.w};
            float a2  [4] = {v2.x,  v2.y,  v2.z,  v2.w};
            float a3  [4] = {v3.x,  v3.y,  v3.z,  v3.w};

            int base = r * LSTRIDE + c * 4;
            #pragma unroll
            for (int k = 0; k < 4; ++k) {
                float im = qv ? __expf(aim[k]) : 0.0f;   // im=0 kills invalid cells
                float txv = (float)(sx0 + k) + aflx[k];
                float tyv = (float)sy + afly[k];
                XY[base + k] = make_float2(txv, tyv);
                IM[base + k] = im;
                HPack hp;
                hp.a = __floats2half2_rn(a0[k] * im, a1[k] * im);
                hp.b = __floats2half2_rn(a2[k] * im, a3[k] * im);
                CH[base + k] = hp;
            }
        }
    }
    __syncthreads();

    // ---------- 2x2 quad register gather: thread owns rows {2qy,2qy+1},
    //            cols {2qx, 2qx+1} of the tile
    const int qx = tid & 15;
    const int qy = tid >> 4;
    const float ox0f = (float)(x0 + 2 * qx);
    const float oy0f = (float)(y0 + 2 * qy);

    float accw[4] = {0.f, 0.f, 0.f, 0.f};
    float acc0[4] = {0.f, 0.f, 0.f, 0.f};
    float acc1[4] = {0.f, 0.f, 0.f, 0.f};
    float acc2[4] = {0.f, 0.f, 0.f, 0.f};
    float acc3[4] = {0.f, 0.f, 0.f, 0.f};

    // staged row r = 2qy + dyi; staged col c = 2qx + 1 + dxi
    for (int dyi = 0; dyi < 8; ++dyi) {
        int rowoff = (2 * qy + dyi) * LSTRIDE + 2 * qx + 1;
        #pragma unroll
        for (int dxi = 0; dxi < 8; ++dxi) {
            float2 xy = XY[rowoff + dxi];
            float ddy = xy.y - oy0f;
            float wy0 = (dyi <= 6) ? fmaxf(0.0f, 1.0f - fabsf(ddy))        : 0.0f;
            float wy1 = (dyi >= 1) ? fmaxf(0.0f, 1.0f - fabsf(ddy - 1.0f)) : 0.0f;
            if (wy0 + wy1 > 0.0f) {
                float ddx = xy.x - ox0f;
                float wx0 = (dxi <= 6) ? fmaxf(0.0f, 1.0f - fabsf(ddx))        : 0.0f;
                float wx1 = (dxi >= 1) ? fmaxf(0.0f, 1.0f - fabsf(ddx - 1.0f)) : 0.0f;
                float t00 = wy0 * wx0, t01 = wy0 * wx1;
                float t10 = wy1 * wx0, t11 = wy1 * wx1;
                if ((t00 + t01) + (t10 + t11) > 0.0f) {   // any-hit
                    float im = IM[rowoff + dxi];
                    HPack hp = CH[rowoff + dxi];
                    float2 f01 = __half22float2(hp.a);
                    float2 f23 = __half22float2(hp.b);
                    accw[0] = fmaf(im, t00, accw[0]);
                    accw[1] = fmaf(im, t01, accw[1]);
                    accw[2] = fmaf(im, t10, accw[2]);
                    accw[3] = fmaf(im, t11, accw[3]);
                    acc0[0] = fmaf(f01.x, t00, acc0[0]);
                    acc0[1] = fmaf(f01.x, t01, acc0[1]);
                    acc0[2] = fmaf(f01.x, t10, acc0[2]);
                    acc0[3] = fmaf(f01.x, t11, acc0[3]);
                    acc1[0] = fmaf(f01.y, t00, acc1[0]);
                    acc1[1] = fmaf(f01.y, t01, acc1[1]);
                    acc1[2] = fmaf(f01.y, t10, acc1[2]);
                    acc1[3] = fmaf(f01.y, t11, acc1[3]);
                    acc2[0] = fmaf(f23.x, t00, acc2[0]);
                    acc2[1] = fmaf(f23.x, t01, acc2[1]);
                    acc2[2] = fmaf(f23.x, t10, acc2[2]);
                    acc2[3] = fmaf(f23.x, t11, acc2[3]);
                    acc3[0] = fmaf(f23.y, t00, acc3[0]);
                    acc3[1] = fmaf(f23.y, t01, acc3[1]);
                    acc3[2] = fmaf(f23.y, t10, acc3[2]);
                    acc3[3] = fmaf(f23.y, t11, acc3[3]);
                }
            }
        }
    }

    // ---------- per-tile bucket merge (mean ~6 entries; aliases smem)
    __syncthreads();
    const int tile = b * NTILE + blockIdx.y * NTILE_X + blockIdx.x;
    int cnt = bcnt[tile];
    if (cnt > BUCKET_CAP) cnt = BUCKET_CAP;
    if (cnt > 0) {                                     // uniform branch
        float* oacc = smem;                            // 5*1024 floats
        for (int i = tid; i < 5 * 1024; i += 256) oacc[i] = 0.0f;
        __syncthreads();
        const float* bb = bucket + (size_t)tile * BUCKET_CAP * 8;
        for (int e = tid; e < cnt; e += 256) {
            const float* ent = bb + (size_t)e * 8;
            int cell = __float_as_int(ent[0]);
            atomicAdd(&oacc[0 * 1024 + cell], ent[1]);
            atomicAdd(&oacc[1 * 1024 + cell], ent[2]);
            atomicAdd(&oacc[2 * 1024 + cell], ent[3]);
            atomicAdd(&oacc[3 * 1024 + cell], ent[4]);
            atomicAdd(&oacc[4 * 1024 + cell], ent[5]);
        }
        __syncthreads();
        #pragma unroll
        for (int k = 0; k < 2; ++k) {
            #pragma unroll
            for (int j = 0; j < 2; ++j) {
                int cell = (2 * qy + k) * TX + 2 * qx + j;
                int a = k * 2 + j;
                acc0[a] += oacc[0 * 1024 + cell];
                acc1[a] += oacc[1 * 1024 + cell];
                acc2[a] += oacc[2 * 1024 + cell];
                acc3[a] += oacc[3 * 1024 + cell];
                accw[a] += oacc[4 * 1024 + cell];
            }
        }
    }

    // ---------- fused normalize + float2 stores (lanes qx-consecutive)
    float inv[4];
    #pragma unroll
    for (int a = 0; a < 4; ++a) inv[a] = 1.0f / (accw[a] + EPS);

    #pragma unroll
    for (int k = 0; k < 2; ++k) {
        size_t obase = (size_t)b * CHW + (size_t)(y0 + 2 * qy + k) * W + (x0 + 2 * qx);
        int a0i = k * 2, a1i = k * 2 + 1;
        *(float2*)(out + obase + 0 * HW) = make_float2(acc0[a0i] * inv[a0i], acc0[a1i] * inv[a1i]);
        *(float2*)(out + obase + 1 * HW) = make_float2(acc1[a0i] * inv[a0i], acc1[a1i] * inv[a1i]);
        *(float2*)(out + obase + 2 * HW) = make_float2(acc2[a0i] * inv[a0i], acc2[a1i] * inv[a1i]);
        *(float2*)(out + obase + 3 * HW) = make_float2(acc3[a0i] * inv[a0i], acc3[a1i] * inv[a1i]);
    }
}

extern "C" void kernel_launch(void* const* d_in, const int* in_sizes, int n_in,
                              void* d_out, int out_size, void* d_ws, size_t ws_size,
                              hipStream_t stream) {
    const float* frame = (const float*)d_in[0];
    const float* flow  = (const float*)d_in[1];
    const float* imp   = (const float*)d_in[2];
    float* out = (float*)d_out;

    int*   bcnt   = (int*)d_ws;                         // 3840 * 4 B
    float* bucket = (float*)((char*)d_ws + 16384);      // 3840*64*32 B = 7.9 MB

    hipMemsetAsync(bcnt, 0, B * NTILE * sizeof(int), stream);

    outlier_pass<<<(NPIX / 4 + 255) / 256, 256, 0, stream>>>(frame, flow, imp, bcnt, bucket);

    dim3 grid(W / TX, H / TY, B);   // 30 x 16 x 8
    splat_gather<<<grid, 256, 0, stream>>>(frame, flow, imp, out, bcnt, bucket);
}